// Round 24
// baseline (61.438 us; speedup 1.0000x reference)
//
#include <hip/hip_runtime.h>
#include <math.h>

#define BATCH 512
#define MAXLEN 80
#define LATENT 10
#define HID 64
#define NSTEPS 100
#define DT 0.01f
#define OUTOFF (BATCH * MAXLEN * LATENT)
#define NSTRIDE (BATCH * LATENT)

typedef __attribute__((ext_vector_type(8))) short s16x8;   // 8 bf16 = 4 VGPRs
typedef __attribute__((ext_vector_type(4))) float f32x4;
typedef __attribute__((ext_vector_type(4))) int   i32x4;
typedef __attribute__((ext_vector_type(2))) float v2f;

__device__ __forceinline__ int cvtpk(float lo, float hi) {
    int r;
    asm("v_cvt_pk_bf16_f32 %0, %1, %2" : "=v"(r) : "v"(lo), "v"(hi));
    return r;
}
// ReLU on packed bf16 pair (positive bf16 order-isomorphic to int16)
__device__ __forceinline__ int pkrelu(int x, int z) {
    int r;
    asm("v_pk_max_i16 %0, %1, %2" : "=v"(r) : "v"(x), "v"(z));
    return r;
}
__device__ __forceinline__ s16x8 mk8(int a, int b, int c, int d) {
    i32x4 v; v.x = a; v.y = b; v.z = c; v.w = d;
    return __builtin_bit_cast(s16x8, v);
}
__device__ __forceinline__ v2f mkv(float a, float b) { v2f r; r.x = a; r.y = b; return r; }
__device__ __forceinline__ v2f fma2(v2f a, v2f b, v2f c) { return __builtin_elementwise_fma(a, b, c); }

#define SETUP(J) \
    float mur##J, is##J, cv##J, cw##J, mb##J; { \
        const int dd_ = (db + (J) < LATENT) ? db + (J) : 0; \
        float zm = z_mean[base + dd_]; \
        float zp = lp ? z_mean[base - LATENT + dd_] : 0.f; \
        float zv = z_log_var[base + dd_]; \
        float zq = lp ? z_log_var[base - LATENT + dd_] : 0.f; \
        float mx = fmaxf(zv, zq); \
        float sg = mx + log1pf(expf(-fabsf(zv - zq))); \
        float sd = expf(0.5f * sg); \
        mur##J = zm - zp; is##J = 1.f / sg; cv##J = 0.5f * DT * sd * sd; \
        cw##J = sd * 0.1f; mb##J = mur##J * DT; }

#define EPP(P, CU, SC) { \
    const v2f sc_ = (SC); \
    const v2f t1_ = mur##P - xs##P; \
    const v2f ld_ = t1_ * is##P; \
    const v2f df_ = ld_ - sc_; \
    er##P = fma2(df_, df_, er##P); \
    const v2f ob_ = fma2(cw##P, (CU), mb##P); \
    xs##P = xs##P + fma2(cv##P, sc_, ob_); }

// one SDE step consuming noise buffers (NAv,NBv); optionally prefetching
// 4-steps-ahead into the same buffers (DO_PF is a literal 0/1).
// sched_barrier(0) after the prefetch pins the loads at their early source
// position (the compiler otherwise may sink them to just before use,
// re-exposing HBM latency every step -- R18's residual stall theory).
// setprio(1) around the MFMA cluster: T5, our waves are unsynced/independent
// (the regime where it measured +4-7%).
#define STEPM(NAv, NBv, DO_PF) { \
    const v2f cu01 = mkv(NAv.x, NAv.y); \
    const v2f cu23 = mkv(NBv.x, NBv.y); \
    if (DO_PF) { \
        NAv = *(const float2*)(nbp + offA); \
        NBv = *(const float2*)(nbp + offB); \
        nbp += NSTRIDE; \
    } \
    __builtin_amdgcn_sched_barrier(0); \
    const int w0 = cvtpk(xs01.x, xs01.y); \
    const int w1 = cvtpk(xs23.x, xs23.y); \
    const int w2 = kg3 ? cvtpk(tt, 1.0f) : 0; \
    const s16x8 bx = mk8(w0, w1, w2, 0); \
    __builtin_amdgcn_s_setprio(1); \
    const f32x4 h0 = __builtin_amdgcn_mfma_f32_16x16x32_bf16(a10, bx, z4, 0, 0, 0); \
    const f32x4 h1 = __builtin_amdgcn_mfma_f32_16x16x32_bf16(a11, bx, z4, 0, 0, 0); \
    const f32x4 h2 = __builtin_amdgcn_mfma_f32_16x16x32_bf16(a12, bx, z4, 0, 0, 0); \
    const f32x4 h3 = __builtin_amdgcn_mfma_f32_16x16x32_bf16(a13, bx, z4, 0, 0, 0); \
    const s16x8 f0 = mk8(pkrelu(cvtpk(h0[0], h0[1]), zpk), \
                         pkrelu(cvtpk(h0[2], h0[3]), zpk), \
                         pkrelu(cvtpk(h1[0], h1[1]), zpk), \
                         pkrelu(cvtpk(h1[2], h1[3]), zpk)); \
    const s16x8 f1 = mk8(pkrelu(cvtpk(h2[0], h2[1]), zpk), \
                         pkrelu(cvtpk(h2[2], h2[3]), zpk), \
                         pkrelu(cvtpk(h3[0], h3[1]), zpk), \
                         pkrelu(cvtpk(h3[2], h3[3]), zpk)); \
    const f32x4 dA = __builtin_amdgcn_mfma_f32_16x16x32_bf16(a20, f0, b2c, 0, 0, 0); \
    const f32x4 dB = __builtin_amdgcn_mfma_f32_16x16x32_bf16(a21, f1, z4, 0, 0, 0); \
    __builtin_amdgcn_s_setprio(0); \
    const v2f sc01 = mkv(dA[0], dA[1]) + mkv(dB[0], dB[1]); \
    const v2f sc23 = mkv(dA[2], dA[3]) + mkv(dB[2], dB[3]); \
    EPP(01, cu01, sc01) \
    EPP(23, cu23, sc23) \
    tt += DT; }

__global__ __launch_bounds__(64) void vae_sde_kernel(
    const float* __restrict__ z_mean, const float* __restrict__ z_log_var,
    const float* __restrict__ W1, const float* __restrict__ b1,
    const float* __restrict__ W2, const float* __restrict__ b2,
    const float* __restrict__ noise, float* __restrict__ out)
{
    const int lane = threadIdx.x;      // 0..63
    const int kg   = lane >> 4;        // K-group 0..3
    const int ci   = lane & 15;        // chain col
    const int c    = blockIdx.x * 16 + ci;
    const int l    = c >> 9;
    const int bb   = c & 511;
    const int base = (bb * MAXLEN + l) * LATENT;
    const bool lp  = (l > 0);
    const int  db  = kg * 4;
    const bool kg3 = (kg == 3);

    SETUP(0) SETUP(1) SETUP(2) SETUP(3)

    const v2f mur01 = mkv(mur0, mur1), mur23 = mkv(mur2, mur3);
    const v2f is01  = mkv(is0,  is1),  is23  = mkv(is2,  is3);
    const v2f cv01  = mkv(cv0,  cv1),  cv23  = mkv(cv2,  cv3);
    const v2f cw01  = mkv(cw0,  cw1),  cw23  = mkv(cw2,  cw3);
    const v2f mb01  = mkv(mb0,  mb1),  mb23  = mkv(mb2,  mb3);
    v2f xs01 = mur01, xs23 = mur23;
    v2f er01 = mkv(0.f, 0.f), er23 = mkv(0.f, 0.f);

    f32x4 z4;
    z4[0] = 0.f; z4[1] = 0.f; z4[2] = 0.f; z4[3] = 0.f;
    const int zpk = 0;

    f32x4 b2c;
    #pragma unroll
    for (int r = 0; r < 4; ++r)
        b2c[r] = (db + r < LATENT) ? b2[db + r] : 0.f;

    #define MKA1(MT, VAR) \
        s16x8 VAR; { \
            const int col = 16 * (MT) + ci; \
            float v[8]; \
            _Pragma("unroll") \
            for (int i = 0; i < 8; ++i) { \
                int row; \
                if (i < 4)       row = (db + i < LATENT) ? db + i : -2; \
                else if (i == 4) row = kg3 ? 10 : -2; \
                else if (i == 5) row = kg3 ? -1 : -2; \
                else             row = -2; \
                v[i] = (row >= 0) ? W1[row * HID + col] \
                     : (row == -1 ? b1[col] : 0.f); \
            } \
            VAR = mk8(cvtpk(v[0], v[1]), cvtpk(v[2], v[3]), \
                      cvtpk(v[4], v[5]), cvtpk(v[6], v[7])); }
    MKA1(0, a10) MKA1(1, a11) MKA1(2, a12) MKA1(3, a13)
    #undef MKA1

    #define MKA2(Q, VAR) \
        s16x8 VAR; { \
            float v[8]; \
            _Pragma("unroll") \
            for (int i = 0; i < 8; ++i) { \
                const int hr = 16 * (2 * (Q) + (i >> 2)) + db + (i & 3); \
                v[i] = (ci < LATENT) ? W2[hr * LATENT + ci] : 0.f; \
            } \
            VAR = mk8(cvtpk(v[0], v[1]), cvtpk(v[2], v[3]), \
                      cvtpk(v[4], v[5]), cvtpk(v[6], v[7])); }
    MKA2(0, a20) MKA2(1, a21)
    #undef MKA2

    // ---- noise: 4-step-deep prefetch (proven R18 pattern) ----
    const int offA = (kg == 0) ? 0 : (kg == 1) ? 4 : 8;
    const int offB = (kg == 0) ? 2 : (kg == 1) ? 6 : 8;
    const float* nb = noise + ((size_t)l * NSTEPS * BATCH + bb) * LATENT;

    float2 nA0 = *(const float2*)(nb + offA);
    float2 nB0 = *(const float2*)(nb + offB);
    float2 nA1 = *(const float2*)(nb + NSTRIDE + offA);
    float2 nB1 = *(const float2*)(nb + NSTRIDE + offB);
    float2 nA2 = *(const float2*)(nb + 2 * NSTRIDE + offA);
    float2 nB2 = *(const float2*)(nb + 2 * NSTRIDE + offB);
    float2 nA3 = *(const float2*)(nb + 3 * NSTRIDE + offA);
    float2 nB3 = *(const float2*)(nb + 3 * NSTRIDE + offB);
    const float* nbp = nb + 4 * NSTRIDE;   // next row to prefetch (s+4)

    float tt = (float)l * DT;

    // 24 iterations x 4 steps (s=0..95), prefetching s+4 each step
    #pragma unroll 1
    for (int it = 0; it < 24; ++it) {
        STEPM(nA0, nB0, 1)
        STEPM(nA1, nB1, 1)
        STEPM(nA2, nB2, 1)
        STEPM(nA3, nB3, 1)
    }
    // epilogue: s=96..99, no prefetch
    STEPM(nA0, nB0, 0)
    STEPM(nA1, nB1, 0)
    STEPM(nA2, nB2, 0)
    STEPM(nA3, nB3, 0)

    const v2f e01 = er01 * (1.0f / NSTEPS);
    const v2f e23 = er23 * (1.0f / NSTEPS);
    if (db < 8) {
        *(float2*)(out + base + db)              = make_float2(xs01.x, xs01.y);
        *(float2*)(out + base + db + 2)          = make_float2(xs23.x, xs23.y);
        *(float2*)(out + OUTOFF + base + db)     = make_float2(e01.x, e01.y);
        *(float2*)(out + OUTOFF + base + db + 2) = make_float2(e23.x, e23.y);
    } else if (kg == 2) {
        *(float2*)(out + base + 8)          = make_float2(xs01.x, xs01.y);
        *(float2*)(out + OUTOFF + base + 8) = make_float2(e01.x, e01.y);
    }
}

extern "C" void kernel_launch(void* const* d_in, const int* in_sizes, int n_in,
                              void* d_out, int out_size, void* d_ws, size_t ws_size,
                              hipStream_t stream) {
    const float* z_mean    = (const float*)d_in[0];
    const float* z_log_var = (const float*)d_in[1];
    const float* W1 = (const float*)d_in[2];
    const float* b1 = (const float*)d_in[3];
    const float* W2 = (const float*)d_in[4];
    const float* b2 = (const float*)d_in[5];
    const float* noise = (const float*)d_in[6];
    float* out = (float*)d_out;

    vae_sde_kernel<<<dim3(2560), dim3(64), 0, stream>>>(
        z_mean, z_log_var, W1, b1, W2, b2, noise, out);
}